// Round 11
// baseline (114.169 us; speedup 1.0000x reference)
//
#include <hip/hip_runtime.h>
#include <cstdint>

// CapsuleLayer dynamic routing: B=256, R=1152, C=10, O=16, I=8, 3 iters.
// Round 11: GG=4 — the per-CU byte-ingest test.
//  * THEORY: rounds 4-10 all pin at ~59us regardless of occupancy, bank
//    conflicts, scratch, or u residency. The invariant is BYTES/CU:
//    each block streams its 576KB W-slice; 5 blocks/CU = 3.2MB through
//    the CU's vector-ingest path at ~20-26 B/cy = the 59us floor.
//  * GG 2->4: one block serves 4 batches per W read. Blocks 1280->640,
//    per-CU ingest 3.2->1.8MB, W chip-traffic 737->368 MB. Predict
//    dur 59 -> 38-46us; if ~59 persists the theory is falsified.
//  * Structure = r6's PROVEN LDS-u design (zero scratch): u[4][1152][8]
//    packed bf16 words = 147KB dynamic LDS -> 1 block/CU (12 waves;
//    r0->r1 showed 12 waves hides latency fine). Phase 2: waves wv
//    split 4 g-groups x 3 waves, 24 iters of ds_read_b64 each.
//  * Same dot association + cvtpk RNE grid as r6/r7 (absmax ~0.00732).
#define BB 256
#define RR 1152
#define CC 10
#define OO 16
#define II 8
#define NT 768
#define GG 4
#define NWAVE (NT / 64)    // 12
#define WPG (NWAVE / GG)   // 3 waves per g in phase 2
#define LOG2E 1.4426950408889634f

typedef float float2v __attribute__((ext_vector_type(2)));

__device__ __forceinline__ void unpack2(uint32_t pk, float& lo, float& hi) {
    union { uint32_t i; float f; } a, b;
    a.i = pk << 16; b.i = pk & 0xffff0000u;
    lo = a.f; hi = b.f;
}
// dot4 via packed f32: pk_mul + pk_fma + hadd (same association as r6-r10)
__device__ __forceinline__ float dot4pk(float4 a, float4 b) {
    float2v al = { a.x, a.y }, ah = { a.z, a.w };
    float2v bl = { b.x, b.y }, bh = { b.z, b.w };
    float2v h = __builtin_elementwise_fma(ah, bh, al * bl);
    return h.x + h.y;
}
// v + (value from lane l^1), DPP quad_perm [1,0,3,2] — VALU pipe
__device__ __forceinline__ float qpadd1(float v) {
    int o = __builtin_amdgcn_mov_dpp(__float_as_int(v), 0xB1, 0xF, 0xF, true);
    return v + __int_as_float(o);
}
// v + (value from lane l^2), DPP quad_perm [2,3,0,1]
__device__ __forceinline__ float qpadd2(float v) {
    int o = __builtin_amdgcn_mov_dpp(__float_as_int(v), 0x4E, 0xF, 0xF, true);
    return v + __int_as_float(o);
}
// value from lane l^2 (float), DPP quad_perm [2,3,0,1]
__device__ __forceinline__ float dppx2f(float v) {
    return __int_as_float(__builtin_amdgcn_mov_dpp(__float_as_int(v), 0x4E, 0xF, 0xF, true));
}
// packed bf16 pair from two f32 (hardware RNE), one instruction
__device__ __forceinline__ uint32_t cvtpk(float lo, float hi) {
    uint32_t r;
    asm("v_cvt_pk_bf16_f32 %0, %1, %2" : "=v"(r) : "v"(lo), "v"(hi));
    return r;
}
#if __has_builtin(__builtin_amdgcn_exp2f)
#define EXP2(x) __builtin_amdgcn_exp2f(x)
#else
#define EXP2(x) __expf((x) * 0.6931471805599453f)
#endif
#define LD4(P) (*reinterpret_cast<const float4*>(P))

// one phase-1 g-slice: dots vs x-vector XV, accumulate, pack, store
#define P1G(XV, SG0, SG1, SG2, SG3, WR)                                       \
  do {                                                                        \
    float d0 = qpadd1(dot4pk(w0, XV));                                        \
    float d1 = qpadd1(dot4pk(w1, XV));                                        \
    float d2 = qpadd1(dot4pk(w2, XV));                                        \
    float d3 = qpadd1(dot4pk(w3, XV));                                        \
    SG0 += d0; SG1 += d1; SG2 += d2; SG3 += d3;                               \
    float sa = pb1 ? (pb0 ? d3 : d2) : (pb0 ? d1 : d0);                       \
    float sb = pb1 ? (pb0 ? d1 : d0) : (pb0 ? d3 : d2);                       \
    (WR)[(size_t)it * 768] = cvtpk(sa, dppx2f(sb));                           \
  } while (0)

__global__ __launch_bounds__(NT, 3)   // 1 block/CU (LDS-limited anyway)
void k_caps(const float* __restrict__ x, const float* __restrict__ W,
            float* __restrict__ out) {
    extern __shared__ uint32_t u2[];          // [GG][RR][8] packed bf16 pairs
    __shared__ float part[NWAVE][17];         // g implied by wv/WPG
    __shared__ float p0s[NWAVE][8][4][GG];    // [wv][lane][j][g]
    __shared__ float wsum[GG][OO];

    const int t = threadIdx.x;
    const int c  = blockIdx.x / (BB / GG);    // BB/GG = 64
    const int b0 = (blockIdx.x % (BB / GG)) * GG;
    const int wv = t >> 6, l = t & 63;
    const int rg = t >> 3, p = t & 7;         // phase 1: 96 r-rows x 8 lanes

    uint32_t* uA = u2;
    uint32_t* uB = u2 + (size_t)RR * 8;
    uint32_t* uC = u2 + (size_t)2 * RR * 8;
    uint32_t* uD = u2 + (size_t)3 * RR * 8;

    const int pos = (p >> 1) + ((p & 1) << 2);
    uint32_t* wrA = uA + (size_t)rg * 8 + pos;
    uint32_t* wrB = uB + (size_t)rg * 8 + pos;
    uint32_t* wrC = uC + (size_t)rg * 8 + pos;
    uint32_t* wrD = uD + (size_t)rg * 8 + pos;
    const bool pb0 = (p & 1) != 0, pb1 = (p & 2) != 0;

    // ---- Phase 1: u -> LDS for 4 batches; fused pass-0 sums ----
    float s00 = 0.f, s01 = 0.f, s02 = 0.f, s03 = 0.f;
    float s10 = 0.f, s11 = 0.f, s12 = 0.f, s13 = 0.f;
    float s20 = 0.f, s21 = 0.f, s22 = 0.f, s23 = 0.f;
    float s30 = 0.f, s31 = 0.f, s32 = 0.f, s33 = 0.f;
#pragma unroll 2
    for (int it = 0; it < 12; ++it) {
        const int r = it * 96 + rg;
        const float* wrow = W + ((size_t)r * CC + c) * (OO * II) + p * 4;
        float4 w0 = LD4(wrow);
        float4 w1 = LD4(wrow + 32);
        float4 w2 = LD4(wrow + 64);
        float4 w3 = LD4(wrow + 96);
        const float* xp = x + ((size_t)b0 * RR + r) * II + (p & 1) * 4;
        float4 xa = LD4(xp);
        float4 xb = LD4(xp + (size_t)RR * II);
        float4 xc = LD4(xp + (size_t)2 * RR * II);
        float4 xd = LD4(xp + (size_t)3 * RR * II);
        P1G(xa, s00, s01, s02, s03, wrA);
        P1G(xb, s10, s11, s12, s13, wrB);
        P1G(xc, s20, s21, s22, s23, wrC);
        P1G(xd, s30, s31, s32, s33, wrD);
    }
    // reduce pass-0 partials over the 8 r-groups of the wave (masks 8,16,32)
#pragma unroll
    for (int m = 8; m < 64; m <<= 1) {
        s00 += __shfl_xor(s00, m); s01 += __shfl_xor(s01, m);
        s02 += __shfl_xor(s02, m); s03 += __shfl_xor(s03, m);
        s10 += __shfl_xor(s10, m); s11 += __shfl_xor(s11, m);
        s12 += __shfl_xor(s12, m); s13 += __shfl_xor(s13, m);
        s20 += __shfl_xor(s20, m); s21 += __shfl_xor(s21, m);
        s22 += __shfl_xor(s22, m); s23 += __shfl_xor(s23, m);
        s30 += __shfl_xor(s30, m); s31 += __shfl_xor(s31, m);
        s32 += __shfl_xor(s32, m); s33 += __shfl_xor(s33, m);
    }
    if (l < 8) {          // lane l holds o = 4j + (l>>1); dup pairs harmless
        p0s[wv][l][0][0] = s00; p0s[wv][l][1][0] = s01;
        p0s[wv][l][2][0] = s02; p0s[wv][l][3][0] = s03;
        p0s[wv][l][0][1] = s10; p0s[wv][l][1][1] = s11;
        p0s[wv][l][2][1] = s12; p0s[wv][l][3][1] = s13;
        p0s[wv][l][0][2] = s20; p0s[wv][l][1][2] = s21;
        p0s[wv][l][2][2] = s22; p0s[wv][l][3][2] = s23;
        p0s[wv][l][0][3] = s30; p0s[wv][l][1][3] = s31;
        p0s[wv][l][2][3] = s32; p0s[wv][l][3][3] = s33;
    }
    __syncthreads();

    if (t < GG * OO) {   // g = t>>4 (0..3), o = t&15 (wave 0)
        const int g = t >> 4, o = t & 15;
        float s = 0.f;
#pragma unroll
        for (int w = 0; w < NWAVE; ++w) s += p0s[w][2 * (o & 3)][o >> 2][g];
        s *= (1.0f / RR);                     // softmax(0) = 1/R
        float ss = s * s;                     // squash over 16-lane o-group
        ss += __shfl_xor(ss, 1); ss += __shfl_xor(ss, 2);
        ss += __shfl_xor(ss, 4); ss += __shfl_xor(ss, 8);
        wsum[g][o] = s * (ss / ((1.0f + ss) * sqrtf(ss + 1e-7f)));  // v0
    }
    __syncthreads();

    // ---- Phase 2: passes 1 and 2 from LDS; 3 waves per g, 24 iters ----
    const int g2 = wv / WPG;                  // 0..3
    const int wv3 = wv - g2 * WPG;            // 0..2
    const uint32_t* ug = u2 + (size_t)g2 * RR * 8;
    const int q = l & 3;                      // owns o in {2q,2q+1,2q+8,2q+9}
    const int rl = l >> 2;                    // 0..15
    const int rbase = wv3 * 16 + rl;          // 0..47
    const uint32_t* rp = ug + (size_t)rbase * 8 + 2 * q;   // words 2q,2q+1

    for (int pass = 1; pass < 3; ++pass) {
        // routing weights pre-scaled by log2(e): exp2(lg) == exp(raw)
        const float2v WQA = { wsum[g2][2 * q] * LOG2E,
                              wsum[g2][2 * q + 8] * LOG2E };
        const float2v WQB = { wsum[g2][2 * q + 1] * LOG2E,
                              wsum[g2][2 * q + 9] * LOG2E };
        float2v N0 = { 0.f, 0.f }, N1 = { 0.f, 0.f };
        float den = 0.f;

#pragma unroll
        for (int it2 = 0; it2 < 24; ++it2) {
            uint2 pp = *reinterpret_cast<const uint2*>(rp + (size_t)it2 * 384);
            // pp.x = row q (2q lo, 2q+1 hi); pp.y = row q+4 (2q+9 lo, 2q+8 hi)
            float2v P0, P1;
            {
                float u0, u1, u2f, u3;
                unpack2(pp.x, u0, u1);
                unpack2(pp.y, u3, u2f);
                P0.x = u0; P0.y = u2f;        // (u[2q],   u[2q+8])
                P1.x = u1; P1.y = u3;         // (u[2q+1], u[2q+9])
            }
            float2v lg2 = __builtin_elementwise_fma(P0, WQA, P1 * WQB);
            float lg = lg2.x + lg2.y;
            lg = qpadd1(lg);                  // + lane^1 (quad partial)
            lg = qpadd2(lg);                  // + lane^2: full 16-o logit
            float e = EXP2(lg);               // == exp(raw logit)
            den += e;                         // same-q lanes hold distinct r's
            float2v E2 = { e, e };
            N0 = __builtin_elementwise_fma(E2, P0, N0);
            N1 = __builtin_elementwise_fma(E2, P1, N1);
        }

        float n0 = N0.x, n2 = N0.y, n1 = N1.x, n3 = N1.y;
#pragma unroll
        for (int m = 4; m < 64; m <<= 1) {    // 16 same-q lanes: distinct rows
            n0 += __shfl_xor(n0, m); n1 += __shfl_xor(n1, m);
            n2 += __shfl_xor(n2, m); n3 += __shfl_xor(n3, m);
            den += __shfl_xor(den, m);
        }
        if (l < 4) {                          // lane l == q
            part[wv][2 * l]     = n0;
            part[wv][2 * l + 1] = n1;
            part[wv][2 * l + 8] = n2;
            part[wv][2 * l + 9] = n3;
            if (l == 0) part[wv][16] = den;
        }
        __syncthreads();

        if (t < GG * OO) {
            const int g = t >> 4, o = t & 15;
            float nf = 0.f, df = 0.f;
#pragma unroll
            for (int w = 0; w < WPG; ++w) {
                nf += part[WPG * g + w][o];
                df += part[WPG * g + w][16];
            }
            float s = nf / df;
            float ss = s * s;
            ss += __shfl_xor(ss, 1); ss += __shfl_xor(ss, 2);
            ss += __shfl_xor(ss, 4); ss += __shfl_xor(ss, 8);
            float v = s * (ss / ((1.0f + ss) * sqrtf(ss + 1e-7f)));
            if (pass == 2)
                out[((size_t)(b0 + g) * CC + c) * OO + o] = v;
            else
                wsum[g][o] += v;
        }
        __syncthreads();
    }
}

extern "C" void kernel_launch(void* const* d_in, const int* in_sizes, int n_in,
                              void* d_out, int out_size, void* d_ws, size_t ws_size,
                              hipStream_t stream) {
    const float* x = (const float*)d_in[0];  // (B,R,I) fp32
    const float* W = (const float*)d_in[1];  // (R,C,O,I) fp32
    if (n_in >= 2 && in_sizes[0] == RR * CC * OO * II &&
        in_sizes[1] == BB * RR * II) {
        const float* tmp = x; x = W; W = tmp;
    }
    float* out = (float*)d_out;              // (B,1,C,O,1) fp32

    const size_t dyn_lds = (size_t)GG * RR * 8 * 4;   // 147,456 B
    static bool s_attr = false;
    if (!s_attr) {                            // allow >64KB dynamic LDS
        hipFuncSetAttribute(reinterpret_cast<const void*>(k_caps),
                            hipFuncAttributeMaxDynamicSharedMemorySize,
                            (int)dyn_lds);
        s_attr = true;
    }
    k_caps<<<CC * (BB / GG), NT, dyn_lds, stream>>>(x, W, out);
}

// Round 12
// 109.740 us; speedup vs baseline: 1.0404x; 1.0404x over previous
//
#include <hip/hip_runtime.h>
#include <cstdint>

// CapsuleLayer dynamic routing: B=256, R=1152, C=10, O=16, I=8, 3 iters.
// Round 12: barrier-diet — 6 syncthreads -> 3, no serial squash sections.
//  * LEDGER r4-r11: dur ~59us invariant to VALU issue (41-60% busy),
//    occupancy (25-58%), bank conflicts (2.27M->30K), scratch (0-58MB),
//    per-CU bytes (1.8-3.2MB). Remaining suspect: CORRELATED stalls —
//    6 barriers/block (each drains vmcnt/lgkmcnt for all 24 waves) + two
//    32-active-thread squash sections between barrier pairs.
//  * FIX: squash computed REDUNDANTLY by all lanes. Per pass: butterfly;
//    lane<4 stores part2[o][wv]; ONE barrier; every lane computes
//    s(o=l&15) from part2 (broadcast reads), 4-shuffle ss-reduce, squash,
//    then 4 in-wave shuffles gather its own routing weights into REGS
//    (ra..rd; wsum LDS deleted). v0 same treatment from p0s.
//    part2 double-buffered -> no reuse race. Barriers: 1 (u+p0s ready),
//    1 per pass = 3 total.
//  * Phase 1 and phase-2 inner loop = r11's clean codegen (indexed loads,
//    no prefetch -> zero scratch), GG=2, 768 thr, 73.7KB dyn LDS,
//    2 blocks/CU. Same arithmetic order -> absmax 0.007324 unchanged.
#define BB 256
#define RR 1152
#define CC 10
#define OO 16
#define II 8
#define NT 768
#define GG 2
#define NWAVE (NT / 64)    // 12
#define WPG (NWAVE / GG)   // 6 waves per g in phase 2
#define LOG2E 1.4426950408889634f

typedef float float2v __attribute__((ext_vector_type(2)));

__device__ __forceinline__ void unpack2(uint32_t pk, float& lo, float& hi) {
    union { uint32_t i; float f; } a, b;
    a.i = pk << 16; b.i = pk & 0xffff0000u;
    lo = a.f; hi = b.f;
}
// dot4 via packed f32: pk_mul + pk_fma + hadd (same association as r6-r11)
__device__ __forceinline__ float dot4pk(float4 a, float4 b) {
    float2v al = { a.x, a.y }, ah = { a.z, a.w };
    float2v bl = { b.x, b.y }, bh = { b.z, b.w };
    float2v h = __builtin_elementwise_fma(ah, bh, al * bl);
    return h.x + h.y;
}
// v + (value from lane l^1), DPP quad_perm [1,0,3,2] — VALU pipe
__device__ __forceinline__ float qpadd1(float v) {
    int o = __builtin_amdgcn_mov_dpp(__float_as_int(v), 0xB1, 0xF, 0xF, true);
    return v + __int_as_float(o);
}
// v + (value from lane l^2), DPP quad_perm [2,3,0,1]
__device__ __forceinline__ float qpadd2(float v) {
    int o = __builtin_amdgcn_mov_dpp(__float_as_int(v), 0x4E, 0xF, 0xF, true);
    return v + __int_as_float(o);
}
// value from lane l^2 (float), DPP quad_perm [2,3,0,1]
__device__ __forceinline__ float dppx2f(float v) {
    return __int_as_float(__builtin_amdgcn_mov_dpp(__float_as_int(v), 0x4E, 0xF, 0xF, true));
}
// packed bf16 pair from two f32 (hardware RNE), one instruction
__device__ __forceinline__ uint32_t cvtpk(float lo, float hi) {
    uint32_t r;
    asm("v_cvt_pk_bf16_f32 %0, %1, %2" : "=v"(r) : "v"(lo), "v"(hi));
    return r;
}
#if __has_builtin(__builtin_amdgcn_exp2f)
#define EXP2(x) __builtin_amdgcn_exp2f(x)
#else
#define EXP2(x) __expf((x) * 0.6931471805599453f)
#endif
#define LD4(P) (*reinterpret_cast<const float4*>(P))

// one phase-1 g-slice: dots vs x-vector XV, accumulate, pack, store
#define P1G(XV, SG0, SG1, SG2, SG3, WR)                                       \
  do {                                                                        \
    float d0 = qpadd1(dot4pk(w0, XV));                                        \
    float d1 = qpadd1(dot4pk(w1, XV));                                        \
    float d2 = qpadd1(dot4pk(w2, XV));                                        \
    float d3 = qpadd1(dot4pk(w3, XV));                                        \
    SG0 += d0; SG1 += d1; SG2 += d2; SG3 += d3;                               \
    float sa = pb1 ? (pb0 ? d3 : d2) : (pb0 ? d1 : d0);                       \
    float sb = pb1 ? (pb0 ? d1 : d0) : (pb0 ? d3 : d2);                       \
    (WR)[(size_t)it * 768] = cvtpk(sa, dppx2f(sb));                           \
  } while (0)

__global__ __launch_bounds__(NT, 6)   // 6 waves/EU cap -> VGPR <= 85
void k_caps(const float* __restrict__ x, const float* __restrict__ W,
            float* __restrict__ out) {
    extern __shared__ uint32_t u2[];          // [GG][RR][8] packed bf16 pairs
    __shared__ float p0s[NWAVE][8][4][GG];    // [wv][lane][j][g]
    __shared__ float part2[2][17][NWAVE];     // [buf][o|den16][wv]

    const int t = threadIdx.x;
    const int c  = blockIdx.x / (BB / GG);    // c-major: blocks share W-slice
    const int b0 = (blockIdx.x % (BB / GG)) * GG;
    const int wv = t >> 6, l = t & 63;
    const int rg = t >> 3, p = t & 7;         // phase 1: 96 r-rows x 8 lanes

    uint32_t* uA = u2;                        // batch b0
    uint32_t* uB = u2 + (size_t)RR * 8;       // batch b0+1

    const int pos = (p >> 1) + ((p & 1) << 2);
    uint32_t* wrA = uA + (size_t)rg * 8 + pos;
    uint32_t* wrB = uB + (size_t)rg * 8 + pos;
    const bool pb0 = (p & 1) != 0, pb1 = (p & 2) != 0;

    // ---- Phase 1: u -> LDS; fused pass-0 sums (r11 clean codegen) ----
    float s00 = 0.f, s01 = 0.f, s02 = 0.f, s03 = 0.f;
    float s10 = 0.f, s11 = 0.f, s12 = 0.f, s13 = 0.f;
#pragma unroll 2
    for (int it = 0; it < 12; ++it) {
        const int r = it * 96 + rg;
        const float* wrow = W + ((size_t)r * CC + c) * (OO * II) + p * 4;
        float4 w0 = LD4(wrow);
        float4 w1 = LD4(wrow + 32);
        float4 w2 = LD4(wrow + 64);
        float4 w3 = LD4(wrow + 96);
        const float* xp = x + ((size_t)b0 * RR + r) * II + (p & 1) * 4;
        float4 xa = LD4(xp);
        float4 xb = LD4(xp + (size_t)RR * II);
        P1G(xa, s00, s01, s02, s03, wrA);
        P1G(xb, s10, s11, s12, s13, wrB);
    }
    // reduce pass-0 partials over the 8 r-groups of the wave (masks 8,16,32)
#pragma unroll
    for (int m = 8; m < 64; m <<= 1) {
        s00 += __shfl_xor(s00, m); s01 += __shfl_xor(s01, m);
        s02 += __shfl_xor(s02, m); s03 += __shfl_xor(s03, m);
        s10 += __shfl_xor(s10, m); s11 += __shfl_xor(s11, m);
        s12 += __shfl_xor(s12, m); s13 += __shfl_xor(s13, m);
    }
    if (l < 8) {          // lane l holds o = 4j + (l>>1); dup pairs harmless
        p0s[wv][l][0][0] = s00; p0s[wv][l][1][0] = s01;
        p0s[wv][l][2][0] = s02; p0s[wv][l][3][0] = s03;
        p0s[wv][l][0][1] = s10; p0s[wv][l][1][1] = s11;
        p0s[wv][l][2][1] = s12; p0s[wv][l][3][1] = s13;
    }
    __syncthreads();                          // BARRIER 1 of 3 (u + p0s ready)

    // ---- Phase-2 mapping ----
    const int g2 = wv / WPG;                  // waves 0-5: g=0, 6-11: g=1
    const int wv6 = wv - g2 * WPG;
    const uint32_t* ug = g2 ? uB : uA;
    const int q = l & 3;                      // owns o in {2q,2q+1,2q+8,2q+9}
    const int rl = l >> 2;
    const int rbase = wv6 * 16 + rl;
    const uint32_t* rp = ug + (size_t)rbase * 8 + 2 * q;

    const int oo = l & 15;                    // lane's redundant-squash o
    const int gb = l & 48;                    // 16-group base for gathers
    const int t0 = gb | (2 * q), t1 = gb | (2 * q + 1);
    const int t2 = gb | (2 * q + 8), t3 = gb | (2 * q + 9);

    // ---- v0, computed by ALL lanes (no serial section, no barrier) ----
    float ra, rb, rc, rd;                     // running routing weights (raw)
    {
        float sv = 0.f;
#pragma unroll
        for (int w = 0; w < NWAVE; ++w) sv += p0s[w][2 * (oo & 3)][oo >> 2][g2];
        sv *= (1.0f / RR);                    // softmax(0) = 1/R
        float ss = sv * sv;
        ss += __shfl_xor(ss, 1); ss += __shfl_xor(ss, 2);
        ss += __shfl_xor(ss, 4); ss += __shfl_xor(ss, 8);
        float vv = sv * (ss / ((1.0f + ss) * sqrtf(ss + 1e-7f)));
        ra = __shfl(vv, t0); rb = __shfl(vv, t1);
        rc = __shfl(vv, t2); rd = __shfl(vv, t3);
    }

    // ---- Phase 2: passes 1 and 2; ONE barrier each ----
#pragma unroll
    for (int pass = 1; pass < 3; ++pass) {
        const float2v WQA = { ra * LOG2E, rc * LOG2E };
        const float2v WQB = { rb * LOG2E, rd * LOG2E };
        float2v N0 = { 0.f, 0.f }, N1 = { 0.f, 0.f };
        float den = 0.f;

#pragma unroll
        for (int it2 = 0; it2 < 12; ++it2) {
            uint2 pp = *reinterpret_cast<const uint2*>(rp + (size_t)it2 * 768);
            // pp.x = row q (2q lo, 2q+1 hi); pp.y = row q+4 (2q+9 lo, 2q+8 hi)
            float u0, u1, u2f, u3;
            unpack2(pp.x, u0, u1);
            unpack2(pp.y, u3, u2f);
            float2v P0 = { u0, u2f };         // (u[2q],   u[2q+8])
            float2v P1 = { u1, u3 };          // (u[2q+1], u[2q+9])
            float2v lg2 = __builtin_elementwise_fma(P0, WQA, P1 * WQB);
            float lg = lg2.x + lg2.y;
            lg = qpadd1(lg);                  // + lane^1 (quad partial)
            lg = qpadd2(lg);                  // + lane^2: full 16-o logit
            float e = EXP2(lg);               // == exp(raw logit)
            den += e;                         // same-q lanes: distinct r's
            float2v E2 = { e, e };
            N0 = __builtin_elementwise_fma(E2, P0, N0);
            N1 = __builtin_elementwise_fma(E2, P1, N1);
        }

        float n0 = N0.x, n2 = N0.y, n1 = N1.x, n3 = N1.y;
#pragma unroll
        for (int m = 4; m < 64; m <<= 1) {    // 16 same-q lanes: distinct rows
            n0 += __shfl_xor(n0, m); n1 += __shfl_xor(n1, m);
            n2 += __shfl_xor(n2, m); n3 += __shfl_xor(n3, m);
            den += __shfl_xor(den, m);
        }
        const int pb = pass & 1;
        if (l < 4) {                          // lane l == q
            part2[pb][2 * l][wv]     = n0;
            part2[pb][2 * l + 1][wv] = n1;
            part2[pb][2 * l + 8][wv] = n2;
            part2[pb][2 * l + 9][wv] = n3;
            if (l == 0) part2[pb][16][wv] = den;
        }
        __syncthreads();                      // BARRIER 2/3 of 3

        // redundant squash by ALL lanes (reads are broadcast/2-way)
        const float* po = &part2[pb][oo][0];
        const float* pd = &part2[pb][16][0];
        float nf = 0.f, df = 0.f;
#pragma unroll
        for (int w = 0; w < WPG; ++w) {
            nf += po[g2 * WPG + w];
            df += pd[g2 * WPG + w];
        }
        float s2 = nf / df;
        float ss2 = s2 * s2;
        ss2 += __shfl_xor(ss2, 1); ss2 += __shfl_xor(ss2, 2);
        ss2 += __shfl_xor(ss2, 4); ss2 += __shfl_xor(ss2, 8);
        float vv2 = s2 * (ss2 / ((1.0f + ss2) * sqrtf(ss2 + 1e-7f)));

        if (pass == 1) {                      // accumulate weights in regs
            ra += __shfl(vv2, t0); rb += __shfl(vv2, t1);
            rc += __shfl(vv2, t2); rd += __shfl(vv2, t3);
        } else {                              // store: wave 0 -> g0, wave 6 -> g1
            if ((wv == 0 || wv == WPG) && l < 16)
                out[((size_t)(b0 + g2) * CC + c) * OO + oo] = vv2;
        }
    }
}

extern "C" void kernel_launch(void* const* d_in, const int* in_sizes, int n_in,
                              void* d_out, int out_size, void* d_ws, size_t ws_size,
                              hipStream_t stream) {
    const float* x = (const float*)d_in[0];  // (B,R,I) fp32
    const float* W = (const float*)d_in[1];  // (R,C,O,I) fp32
    if (n_in >= 2 && in_sizes[0] == RR * CC * OO * II &&
        in_sizes[1] == BB * RR * II) {
        const float* tmp = x; x = W; W = tmp;
    }
    float* out = (float*)d_out;              // (B,1,C,O,1) fp32

    const size_t dyn_lds = (size_t)GG * RR * 8 * 4;   // 73,728 B
    k_caps<<<CC * (BB / GG), NT, dyn_lds, stream>>>(x, W, out);
}